// Round 1
// baseline (1366.059 us; speedup 1.0000x reference)
//
#include <hip/hip_runtime.h>

#define BUCKET_CAP 128
#define EMB_DIM 128

// One wave (64 lanes) per index:
//  - probe: lane l loads slots 2l, 2l+1 (int2) -> coalesced 512B bucket read
//  - two ballots + ffs find FIRST matching slot (argmax semantics), wave-uniform
//  - gather: lane l loads emb row floats [2l, 2l+1] (float2) -> coalesced 512B
//  - store:  same pattern to out
__global__ __launch_bounds__(256) void emb_hash_lookup_kernel(
    const int* __restrict__ indices,              // [N]
    const int* __restrict__ offsets,              // [F+1]
    const int* __restrict__ bucket_keys,          // [total_buckets, 128]
    const int* __restrict__ table_offsets,        // [T+1]
    const int* __restrict__ table_bucket_offsets, // [T+1]
    const int* __restrict__ num_buckets,          // [T]
    const float* __restrict__ emb,                // [rows, 128]
    float* __restrict__ out,                      // [N, 128]
    int N, int F)
{
    const int lane   = threadIdx.x & 63;
    const int wave   = (int)((blockIdx.x * blockDim.x + threadIdx.x) >> 6);
    const int nwaves = (int)((gridDim.x * blockDim.x) >> 6);

    for (int i = wave; i < N; i += nwaves) {
        const int key = indices[i];

        // feature/table id: offsets[f] <= i < offsets[f+1]  (F is tiny, e.g. 4)
        int tid = 0;
        for (int f = 1; f < F; ++f) tid += (i >= offsets[f]) ? 1 : 0;

        const int nb       = num_buckets[tid];
        const int b_local  = key % nb;                       // keys are >= 0
        const int b_global = table_bucket_offsets[tid] + b_local;

        // ---- probe all 128 slots: 2 per lane, coalesced 512B ----
        const int2* sk = (const int2*)(bucket_keys + (long long)b_global * BUCKET_CAP);
        const int2 kk = sk[lane];
        const unsigned long long m0 = __ballot(kk.x == key);
        const unsigned long long m1 = __ballot(kk.y == key);
        const bool found = (m0 | m1) != 0ull;                // wave-uniform

        float2 val = make_float2(0.0f, 0.0f);
        if (found) {
            // first matching slot (min over even-slot / odd-slot candidates)
            const int s0 = m0 ? ((__ffsll(m0) - 1) << 1)       : (1 << 30);
            const int s1 = m1 ? (((__ffsll(m1) - 1) << 1) | 1) : (1 << 30);
            const int slot = min(s0, s1);
            const long long row = (long long)table_offsets[tid]
                                + (long long)b_local * BUCKET_CAP + slot;
            const float2* er = (const float2*)(emb + row * EMB_DIM);
            val = er[lane];
        }
        ((float2*)out)[(long long)i * (EMB_DIM / 2) + lane] = val;
    }
}

extern "C" void kernel_launch(void* const* d_in, const int* in_sizes, int n_in,
                              void* d_out, int out_size, void* d_ws, size_t ws_size,
                              hipStream_t stream) {
    const int*   indices              = (const int*)d_in[0];
    const int*   offsets              = (const int*)d_in[1];
    const int*   bucket_keys          = (const int*)d_in[2];
    const int*   table_offsets        = (const int*)d_in[3];
    const int*   table_bucket_offsets = (const int*)d_in[4];
    const int*   num_buckets          = (const int*)d_in[5];
    const float* emb                  = (const float*)d_in[6];
    float*       out                  = (float*)d_out;

    const int N = in_sizes[0];
    const int F = in_sizes[1] - 1;

    // 2048 blocks x 256 threads = 8192 waves = 32 waves/CU x 256 CU (full occupancy).
    // Each wave grid-strides over N/8192 indices.
    int blocks = (N + 3) / 4;                 // 4 waves per block, 1 index per wave min
    if (blocks > 2048) blocks = 2048;
    if (blocks < 1) blocks = 1;

    emb_hash_lookup_kernel<<<blocks, 256, 0, stream>>>(
        indices, offsets, bucket_keys, table_offsets, table_bucket_offsets,
        num_buckets, emb, out, N, F);
}